// Round 1
// baseline (632.410 us; speedup 1.0000x reference)
//
#include <hip/hip_runtime.h>
#include <stdint.h>

#define M_CH      384
#define THRESH    3.0f
#define MARGIN_L  20
#define MARGIN_R  20
#define TR        15
#define CHUNK     32
#define HALO      62      // CHUNK + 2*TR
#define STRIP     320     // rows per block; multiple of CHUNK

// ---------------- K0: neighbor lists ----------------
__global__ void nbr_kernel(const float* __restrict__ locs,
                           uint32_t* __restrict__ nbrCount,
                           uint16_t* __restrict__ nbrList) {
    __shared__ float lx[M_CH], ly[M_CH];
    int t = threadIdx.x;
    lx[t] = locs[2 * t];
    ly[t] = locs[2 * t + 1];
    __syncthreads();
    float x = lx[t], y = ly[t];
    int cnt = 0;
    for (int c = 0; c < M_CH; ++c) {
        float dx = x - lx[c], dy = y - ly[c];
        float d = sqrtf(dx * dx + dy * dy);
        if (d <= 100.0f) { nbrList[t * M_CH + cnt] = (uint16_t)c; cnt++; }
    }
    nbrCount[t] = cnt;
}

// ---------------- K1: detect, per-chunk bitmask + counts ----------------
__global__ __launch_bounds__(384, 3)
void detect_kernel(const float* __restrict__ traces, int N,
                   const uint32_t* __restrict__ nbrCount,
                   const uint16_t* __restrict__ nbrList,
                   uint32_t* __restrict__ bitmask,      // [nchunk * 384] words
                   uint32_t* __restrict__ chunkCounts)  // [nchunk]
{
    __shared__ float tmax[CHUNK][M_CH];   // 48 KB
    __shared__ uint32_t bm[M_CH];         // 12288 bits = one chunk's mask
    __shared__ uint32_t cnt;

    const int c = threadIdx.x;            // channel / column
    const int strip0 = blockIdx.x * STRIP;
    const int stripEnd = min(strip0 + STRIP, N);
    const int nnb = (int)nbrCount[c];

    float w[HALO];

    for (int r0 = strip0; r0 < stripEnd; r0 += CHUNK) {
        bm[c] = 0;
        if (c == 0) cnt = 0;
        __syncthreads();

        // load halo rows [r0-15, r0+46] of this column (coalesced across lanes)
        #pragma unroll
        for (int j = 0; j < HALO; ++j) {
            int row = r0 - TR + j;
            float v = -INFINITY;
            if (row >= 0 && row < N) v = -traces[(long)row * M_CH + c];
            w[j] = v;
        }

        // candidate bits (threshold + margin) on RAW values
        uint32_t cand = 0;
        #pragma unroll
        for (int n = 0; n < CHUNK; ++n) {
            int row = r0 + n;
            if (row >= MARGIN_L && row < N - MARGIN_R && w[n + TR] >= THRESH)
                cand |= (1u << n);
        }

        // in-place sliding-max doubling: after these, w[j] = max(orig[j..j+15])
        #pragma unroll
        for (int j = 0; j < HALO - 1; ++j)  w[j] = fmaxf(w[j], w[j + 1]);
        #pragma unroll
        for (int j = 0; j < HALO - 3; ++j)  w[j] = fmaxf(w[j], w[j + 2]);
        #pragma unroll
        for (int j = 0; j < HALO - 7; ++j)  w[j] = fmaxf(w[j], w[j + 4]);
        #pragma unroll
        for (int j = 0; j < HALO - 15; ++j) w[j] = fmaxf(w[j], w[j + 8]);

        // temporal max (31-window centered at r0+n) -> LDS
        #pragma unroll
        for (int n = 0; n < CHUNK; ++n)
            tmax[n][c] = fmaxf(w[n], w[n + TR]);
        __syncthreads();

        // verify rare candidates against neighbor temporal maxima
        while (cand) {
            int n = __ffs(cand) - 1;
            cand &= cand - 1;
            int row = r0 + n;
            float raw = -traces[(long)row * M_CH + c];   // L1/L2 hit, rare
            bool ok = true;
            for (int j = 0; j < nnb; ++j) {
                int c2 = (int)nbrList[c * M_CH + j];
                if (raw < tmax[n][c2]) { ok = false; break; }
            }
            if (ok) {
                int f = n * M_CH + c;
                atomicOr(&bm[f >> 5], 1u << (f & 31));
            }
        }
        __syncthreads();

        // store chunk bitmask + count
        int cidx = r0 >> 5;               // global chunk id (r0 multiple of 32)
        uint32_t wv = bm[c];
        bitmask[(long)cidx * M_CH + c] = wv;
        if (wv) atomicAdd(&cnt, (uint32_t)__popc(wv));
        __syncthreads();
        if (c == 0) chunkCounts[cidx] = cnt;
    }
}

// ---------------- K2: exclusive prefix over chunk counts ----------------
__global__ void scan_kernel(const uint32_t* __restrict__ counts, int n,
                            uint32_t* __restrict__ prefix) {
    __shared__ uint32_t s[256];
    int t = threadIdx.x;
    int per = (n + 255) / 256;
    int lo = t * per, hi = min(lo + per, n);
    uint32_t sum = 0;
    for (int i = lo; i < hi; ++i) sum += counts[i];
    s[t] = sum;
    __syncthreads();
    for (int off = 1; off < 256; off <<= 1) {
        uint32_t v = (t >= off) ? s[t - off] : 0;
        __syncthreads();
        s[t] += v;
        __syncthreads();
    }
    uint32_t run = s[t] - sum;   // exclusive base for this thread's range
    for (int i = lo; i < hi; ++i) { prefix[i] = run; run += counts[i]; }
    if (t == 255) prefix[n] = run;  // total
}

// ---------------- K3: ordered emit ----------------
__global__ void emit_kernel(const uint32_t* __restrict__ bitmask,
                            const uint32_t* __restrict__ chunkPrefix,
                            int maxdet,
                            int* __restrict__ times, int* __restrict__ chans) {
    __shared__ uint32_t s[M_CH];
    int t = threadIdx.x;
    int e = blockIdx.x;                      // chunk id
    uint32_t wv = bitmask[(long)e * M_CH + t];
    uint32_t pc = (uint32_t)__popc(wv);
    s[t] = pc;
    __syncthreads();
    for (int off = 1; off < M_CH; off <<= 1) {
        uint32_t v = (t >= off) ? s[t - off] : 0;
        __syncthreads();
        s[t] += v;
        __syncthreads();
    }
    int base = (int)chunkPrefix[e] + (int)(s[t] - pc);
    int r0 = e * CHUNK;
    while (wv) {
        int b = __ffs(wv) - 1;
        wv &= wv - 1;
        int f = t * 32 + b;
        int n = f / M_CH;
        int ch = f - n * M_CH;
        if (base < maxdet) {
            times[base] = r0 + n;
            chans[base] = ch;
        }
        base++;
    }
}

// ---------------- K4: fill tail with -1 ----------------
__global__ void fill_kernel(const uint32_t* __restrict__ totalPtr, int maxdet,
                            int* __restrict__ times, int* __restrict__ chans) {
    int i = blockIdx.x * blockDim.x + threadIdx.x;
    int total = (int)*totalPtr;
    if (i < maxdet && i >= total) { times[i] = -1; chans[i] = -1; }
}

extern "C" void kernel_launch(void* const* d_in, const int* in_sizes, int n_in,
                              void* d_out, int out_size, void* d_ws, size_t ws_size,
                              hipStream_t stream) {
    const float* traces = (const float*)d_in[0];
    const float* locs   = (const float*)d_in[1];
    const int M = M_CH;
    const int N = in_sizes[0] / M;          // 150000
    const int maxdet = out_size / 2;        // 100000
    int* times = (int*)d_out;
    int* chans = times + maxdet;

    const int nchunk = (N + CHUNK - 1) / CHUNK;   // 4688
    char* ws = (char*)d_ws;
    uint32_t* nbrCount    = (uint32_t*)ws;                        // 384*4
    uint16_t* nbrList     = (uint16_t*)(ws + 1536);               // 384*384*2
    uint32_t* chunkCounts = (uint32_t*)(ws + 1536 + 294912);      // nchunk
    uint32_t* chunkPrefix = chunkCounts + nchunk;                 // nchunk+1
    uint32_t* bitmask     = chunkPrefix + nchunk + 1;             // nchunk*384 words

    nbr_kernel<<<1, M_CH, 0, stream>>>(locs, nbrCount, nbrList);

    int nblk = (N + STRIP - 1) / STRIP;      // 469
    detect_kernel<<<nblk, M_CH, 0, stream>>>(traces, N, nbrCount, nbrList,
                                             bitmask, chunkCounts);

    scan_kernel<<<1, 256, 0, stream>>>(chunkCounts, nchunk, chunkPrefix);

    emit_kernel<<<nchunk, M_CH, 0, stream>>>(bitmask, chunkPrefix, maxdet,
                                             times, chans);

    fill_kernel<<<(maxdet + 255) / 256, 256, 0, stream>>>(chunkPrefix + nchunk,
                                                          maxdet, times, chans);
}

// Round 2
// 511.723 us; speedup vs baseline: 1.2358x; 1.2358x over previous
//
#include <hip/hip_runtime.h>
#include <stdint.h>

#define M_CH      384
#define THRESH    3.0f      // detect on -traces >= 3  <=>  traces <= -3
#define MARGIN    20
#define TR        15
#define CHUNK     16
#define HALO      46        // CHUNK + 2*TR
#define BM_WORDS  192       // CHUNK*M_CH/32 bits per chunk

// ---------------- K0: neighbor lists ----------------
__global__ void nbr_kernel(const float* __restrict__ locs,
                           uint32_t* __restrict__ nbrCount,
                           uint16_t* __restrict__ nbrList) {
    __shared__ float lx[M_CH], ly[M_CH];
    int t = threadIdx.x;
    lx[t] = locs[2 * t];
    ly[t] = locs[2 * t + 1];
    __syncthreads();
    float x = lx[t], y = ly[t];
    int cnt = 0;
    for (int c = 0; c < M_CH; ++c) {
        float dx = x - lx[c], dy = y - ly[c];
        float d = sqrtf(dx * dx + dy * dy);
        if (d <= 100.0f) { nbrList[t * M_CH + cnt] = (uint16_t)c; cnt++; }
    }
    nbrCount[t] = cnt;
}

// ---------------- K1: detect (one 16-row chunk per block) ----------------
// LDS halo staging (coalesced float4) -> per-thread register sliding-min
// (doubling) -> tmin back to LDS -> rare candidate verify vs neighbors.
__global__ __launch_bounds__(384, 3)
void detect_kernel(const float* __restrict__ traces, int N,
                   const uint32_t* __restrict__ nbrCount,
                   const uint16_t* __restrict__ nbrList,
                   uint32_t* __restrict__ bitmask,      // [nchunk * BM_WORDS]
                   uint32_t* __restrict__ chunkCounts)  // [nchunk]
{
    __shared__ float HB[HALO * M_CH];     // 70.6 KB halo buffer (raw values)
    __shared__ uint32_t bm[BM_WORDS];
    __shared__ uint32_t cnt;

    const int t = threadIdx.x;
    const int c = t;                      // channel for phase 2
    const int chunk = blockIdx.x;
    const int r0 = chunk * CHUNK;

    if (t < BM_WORDS) bm[t] = 0;
    if (t == 0) cnt = 0;

    // --- cooperative halo load: rows [r0-15, r0+30], clamped at edges.
    // Clamped (fake) rows only influence chunks whose rows are inside the
    // margin (<20 or >=N-20) where no candidate can exist -> harmless.
    const int rloc = t / 96;              // 4 rows per iteration
    const int col4 = t - rloc * 96;       // float4 column
    #pragma unroll
    for (int k = 0; k < 12; ++k) {
        int row = k * 4 + rloc;
        if (row < HALO) {
            int grow = r0 - TR + row;
            grow = min(max(grow, 0), N - 1);
            float4 v = *(const float4*)(traces + (long)grow * M_CH + col4 * 4);
            *(float4*)(&HB[row * M_CH + col4 * 4]) = v;
        }
    }
    __syncthreads();

    // --- per-thread column read (bank-friendly: 2-way, free)
    float w[HALO];
    #pragma unroll
    for (int j = 0; j < HALO; ++j) w[j] = HB[j * M_CH + c];

    float raw[CHUNK];
    #pragma unroll
    for (int n = 0; n < CHUNK; ++n) raw[n] = w[n + TR];

    // sliding-min doubling: after these, w[j] = min(orig[j .. j+15])
    #pragma unroll
    for (int j = 0; j < HALO - 1; ++j)  w[j] = fminf(w[j], w[j + 1]);
    #pragma unroll
    for (int j = 0; j < HALO - 3; ++j)  w[j] = fminf(w[j], w[j + 2]);
    #pragma unroll
    for (int j = 0; j < HALO - 7; ++j)  w[j] = fminf(w[j], w[j + 4]);
    #pragma unroll
    for (int j = 0; j < HALO - 15; ++j) w[j] = fminf(w[j], w[j + 8]);

    __syncthreads();   // everyone done reading HB columns

    // tmin over 31-window centered at chunk row n -> reuse HB rows 0..15
    #pragma unroll
    for (int n = 0; n < CHUNK; ++n)
        HB[n * M_CH + c] = fminf(w[n], w[n + TR]);
    __syncthreads();

    // --- candidates (rare): threshold + margin on raw value
    uint32_t cand = 0;
    #pragma unroll
    for (int n = 0; n < CHUNK; ++n) {
        int row = r0 + n;
        if (row >= MARGIN && row < N - MARGIN && raw[n] <= -THRESH)
            cand |= (1u << n);
    }
    const int nnb = (int)nbrCount[c];
    while (cand) {
        int n = __ffs(cand) - 1;
        cand &= cand - 1;
        float rv = raw[n];
        bool ok = true;
        for (int j = 0; j < nnb; ++j) {
            int c2 = (int)nbrList[c * M_CH + j];
            if (rv > HB[n * M_CH + c2]) { ok = false; break; }
        }
        if (ok) {
            int f = n * M_CH + c;
            atomicOr(&bm[f >> 5], 1u << (f & 31));
        }
    }
    __syncthreads();

    if (t < BM_WORDS) {
        uint32_t wv = bm[t];
        bitmask[(long)chunk * BM_WORDS + t] = wv;
        if (wv) atomicAdd(&cnt, (uint32_t)__popc(wv));
    }
    __syncthreads();
    if (t == 0) chunkCounts[chunk] = cnt;
}

// ---------------- K2: exclusive prefix over chunk counts ----------------
__global__ void scan_kernel(const uint32_t* __restrict__ counts, int n,
                            uint32_t* __restrict__ prefix) {
    __shared__ uint32_t s[256];
    int t = threadIdx.x;
    int per = (n + 255) / 256;
    int lo = t * per, hi = min(lo + per, n);
    uint32_t sum = 0;
    for (int i = lo; i < hi; ++i) sum += counts[i];
    s[t] = sum;
    __syncthreads();
    for (int off = 1; off < 256; off <<= 1) {
        uint32_t v = (t >= off) ? s[t - off] : 0;
        __syncthreads();
        s[t] += v;
        __syncthreads();
    }
    uint32_t run = s[t] - sum;   // exclusive base for this thread's range
    for (int i = lo; i < hi; ++i) { prefix[i] = run; run += counts[i]; }
    if (t == 255) prefix[n] = run;  // total
}

// ---------------- K3: ordered emit, one wave per chunk ----------------
__global__ void emit_kernel(const uint32_t* __restrict__ bitmask,
                            const uint32_t* __restrict__ chunkPrefix,
                            int nchunk, int maxdet,
                            int* __restrict__ times, int* __restrict__ chans) {
    int wv = threadIdx.x >> 6;
    int lane = threadIdx.x & 63;
    int chunkId = blockIdx.x * 4 + wv;
    if (chunkId >= nchunk) return;

    const uint32_t* wp = bitmask + (long)chunkId * BM_WORDS + lane * 3;
    uint32_t b0 = wp[0], b1 = wp[1], b2 = wp[2];
    int p0 = __popc(b0), p1 = __popc(b1), p2 = __popc(b2);
    int local = p0 + p1 + p2;

    // inclusive wave scan via shfl_up
    int s = local;
    #pragma unroll
    for (int off = 1; off < 64; off <<= 1) {
        int v = __shfl_up(s, off, 64);
        if (lane >= off) s += v;
    }
    int base = (int)chunkPrefix[chunkId] + (s - local);
    int r0 = chunkId * CHUNK;

    uint32_t words[3] = { b0, b1, b2 };
    #pragma unroll
    for (int q = 0; q < 3; ++q) {
        uint32_t x = words[q];
        int fbase = (lane * 3 + q) * 32;
        while (x) {
            int b = __ffs(x) - 1;
            x &= x - 1;
            int f = fbase + b;
            int n = f / M_CH;
            int ch = f - n * M_CH;
            if (base < maxdet) {
                times[base] = r0 + n;
                chans[base] = ch;
            }
            base++;
        }
    }
}

// ---------------- K4: fill tail with -1 ----------------
__global__ void fill_kernel(const uint32_t* __restrict__ totalPtr, int maxdet,
                            int* __restrict__ times, int* __restrict__ chans) {
    int i = blockIdx.x * blockDim.x + threadIdx.x;
    int total = (int)*totalPtr;
    if (i < maxdet && i >= total) { times[i] = -1; chans[i] = -1; }
}

extern "C" void kernel_launch(void* const* d_in, const int* in_sizes, int n_in,
                              void* d_out, int out_size, void* d_ws, size_t ws_size,
                              hipStream_t stream) {
    const float* traces = (const float*)d_in[0];
    const float* locs   = (const float*)d_in[1];
    const int M = M_CH;
    const int N = in_sizes[0] / M;          // 150000
    const int maxdet = out_size / 2;        // 100000
    int* times = (int*)d_out;
    int* chans = times + maxdet;

    const int nchunk = (N + CHUNK - 1) / CHUNK;   // 9375
    char* ws = (char*)d_ws;
    uint32_t* nbrCount    = (uint32_t*)ws;                         // 1536 B
    uint16_t* nbrList     = (uint16_t*)(ws + 1536);                // 294912 B
    uint32_t* chunkCounts = (uint32_t*)(ws + 1536 + 294912);       // nchunk
    uint32_t* chunkPrefix = chunkCounts + nchunk;                  // nchunk+1
    uint32_t* bitmask     = chunkPrefix + nchunk + 1;              // nchunk*192

    nbr_kernel<<<1, M_CH, 0, stream>>>(locs, nbrCount, nbrList);

    detect_kernel<<<nchunk, M_CH, 0, stream>>>(traces, N, nbrCount, nbrList,
                                               bitmask, chunkCounts);

    scan_kernel<<<1, 256, 0, stream>>>(chunkCounts, nchunk, chunkPrefix);

    emit_kernel<<<(nchunk + 3) / 4, 256, 0, stream>>>(bitmask, chunkPrefix,
                                                      nchunk, maxdet,
                                                      times, chans);

    fill_kernel<<<(maxdet + 255) / 256, 256, 0, stream>>>(chunkPrefix + nchunk,
                                                          maxdet, times, chans);
}